// Round 6
// baseline (557.961 us; speedup 1.0000x reference)
//
#include <hip/hip_runtime.h>
#include <hip/hip_bf16.h>

#define NN 8192
#define FIN 512
#define FOUT 256
#define JTILE 64
#define FDWIN 2048
#define NWRD (NN / 32)     // 256 mask words per row

typedef __attribute__((ext_vector_type(8))) short short8;
typedef __attribute__((ext_vector_type(4))) float float4v;
typedef __attribute__((ext_vector_type(4))) int int4v;
typedef __attribute__((ext_vector_type(16))) float float16v;

#if __has_builtin(__builtin_amdgcn_exp2f)
#define EXP2(x) __builtin_amdgcn_exp2f(x)
#else
#define EXP2(x) exp2f(x)
#endif

__device__ __forceinline__ short f2bf(float f) {
    union { float f; unsigned u; } v; v.f = f;
    unsigned r = (v.u + 0x7FFFu + ((v.u >> 16) & 1u)) >> 16;
    return (short)r;
}

// pack 2 f32 -> 2 bf16 (RNE), lo -> D[15:0], hi -> D[31:16]
__device__ __forceinline__ unsigned cvt_pk_bf16(float lo, float hi) {
    unsigned r;
    asm("v_cvt_pk_bf16_f32 %0, %1, %2" : "=v"(r) : "v"(lo), "v"(hi));
    return r;
}

// ---------------- Kernel 0: Wt[n][k] = bf16(W[k][n]), tiled transpose ----------------
__global__ __launch_bounds__(256) void wt_kernel(const float* __restrict__ W,
                                                 short* __restrict__ Wt) {
    __shared__ short tile[32][33];
    int tx = threadIdx.x & 31, ty = threadIdx.x >> 5;   // 32 x 8
    int k0 = blockIdx.x * 32, n0 = blockIdx.y * 32;
#pragma unroll
    for (int r = 0; r < 32; r += 8)
        tile[ty + r][tx] = f2bf(W[(size_t)(k0 + ty + r) * FOUT + n0 + tx]);
    __syncthreads();
#pragma unroll
    for (int r = 0; r < 32; r += 8)
        Wt[(size_t)(n0 + ty + r) * FIN + k0 + tx] = tile[tx][ty + r];
}

// ---------------- Kernel 1 (fused): blocks [0,512) = h/f_src/f_dst; [512,2560) = adj->bitmask ----
// mask word w covers adj[w*32 .. w*32+32); bit b = (adj[w*32+b] != 0).
// Mask part: thread reads 4 x 128B contiguous chunks (wave = 8KB contiguous), nt loads,
// writes 8MB mask -> L3-resident for gat. BW-bound stream overlaps latency-bound h part.
__global__ __launch_bounds__(256) void hm_kernel(const float* __restrict__ x,
                                                 const short* __restrict__ Wt,
                                                 const float* __restrict__ a,
                                                 const int* __restrict__ adj,
                                                 short* __restrict__ h_t,
                                                 float* __restrict__ f_src,
                                                 float* __restrict__ f_dst,
                                                 unsigned* __restrict__ mask) {
    if (blockIdx.x >= 512) {
        // ---- mask part ----
        const int mb = blockIdx.x - 512;                 // 0..2047
        size_t w = (size_t)mb * 1024 + threadIdx.x;      // 2048*1024 = 2M words total
#pragma unroll
        for (int it = 0; it < 4; it++, w += 256) {
            const int4v* p = (const int4v*)(adj + (w << 5));
            unsigned m = 0;
#pragma unroll
            for (int g = 0; g < 8; g++) {
                int4v v = __builtin_nontemporal_load(p + g);
                m |= (v[0] != 0 ? 1u : 0u) << (g * 4);
                m |= (v[1] != 0 ? 1u : 0u) << (g * 4 + 1);
                m |= (v[2] != 0 ? 1u : 0u) << (g * 4 + 2);
                m |= (v[3] != 0 ? 1u : 0u) << (g * 4 + 3);
            }
            mask[w] = m;
        }
        return;
    }
    // ---- h part (identical to previous h_kernel) ----
    int wave = (blockIdx.x << 2) + (threadIdx.x >> 6);
    int lane = threadIdx.x & 63;
    int m0 = (wave & 511) << 4;
    int n0 = (wave >> 9) << 6;
    int lr = lane & 15, lq = lane >> 4;

    const float* xrow = x + (size_t)(m0 + lr) * FIN + lq * 8;
    const short* wbase = Wt + (size_t)(n0 + lr) * FIN + lq * 8;

    float4v acc[4] = {};
    for (int k0 = 0; k0 < FIN; k0 += 32) {
        float4v xa = *(const float4v*)(xrow + k0);
        float4v xb = *(const float4v*)(xrow + k0 + 4);
        short8 av;
        av[0] = f2bf(xa[0]); av[1] = f2bf(xa[1]); av[2] = f2bf(xa[2]); av[3] = f2bf(xa[3]);
        av[4] = f2bf(xb[0]); av[5] = f2bf(xb[1]); av[6] = f2bf(xb[2]); av[7] = f2bf(xb[3]);
#pragma unroll
        for (int ct = 0; ct < 4; ct++) {
            short8 bv = *(const short8*)(wbase + (size_t)ct * 16 * FIN + k0);
            acc[ct] = __builtin_amdgcn_mfma_f32_16x16x32_bf16(av, bv, acc[ct], 0, 0, 0);
        }
    }
    float s_part[4] = {0.f, 0.f, 0.f, 0.f};
    float d_part[4] = {0.f, 0.f, 0.f, 0.f};
#pragma unroll
    for (int ct = 0; ct < 4; ct++) {
        int n = n0 + ct * 16 + lr;
        float al = a[n], ar = a[FOUT + n];
#pragma unroll
        for (int reg = 0; reg < 4; reg++) {
            float hv = acc[ct][reg];
            s_part[reg] = fmaf(hv, al, s_part[reg]);
            d_part[reg] = fmaf(hv, ar, d_part[reg]);
            h_t[(size_t)n * NN + (m0 + lq * 4 + reg)] = f2bf(hv);
        }
    }
#pragma unroll
    for (int off = 1; off < 16; off <<= 1) {
#pragma unroll
        for (int reg = 0; reg < 4; reg++) {
            s_part[reg] += __shfl_xor(s_part[reg], off);
            d_part[reg] += __shfl_xor(d_part[reg], off);
        }
    }
    const float LOG2E = 1.4426950408889634f;
    if (lr == 0) {
#pragma unroll
        for (int reg = 0; reg < 4; reg++) {
            atomicAdd(&f_src[m0 + lq * 4 + reg], s_part[reg] * LOG2E);
            atomicAdd(&f_dst[m0 + lq * 4 + reg], d_part[reg] * LOG2E);
        }
    }
}

// ---------------- Kernel 2: fused masked-softmax-numerator @ h (j-sliced) ----------------
// v6: adj replaced by 8MB L3-resident bitmask (1 uint32 load per thread per tile,
// prefetched 1 tile ahead -- L3 latency trivially covered). Frees 15 VGPRs; peak live
// ~130 << 170 @ (256,3). The 256MB adj stream moved to hm_kernel's coalesced pass.
__global__ __launch_bounds__(256, 3) void gat_kernel(const unsigned* __restrict__ mask,
                                                     const short* __restrict__ h_t,
                                                     const float* __restrict__ f_src,
                                                     const float* __restrict__ f_dst,
                                                     float* __restrict__ Opart,
                                                     float* __restrict__ lpart,
                                                     int qt, int rt_) {
    __shared__ short Pt[2][64 * 64];   // [row][j], XOR-swizzled (byte ^= (row&7)<<4), 2x8KB
    __shared__ float Fdall[FDWIN];     // f_dst window (<=8KB), staged once per window

    const int t = threadIdx.x;
    const int i0 = blockIdx.x * 64;
    const int slice = blockIdx.y;
    // slice s covers tiles [s*qt + min(s,rt_), +qt + (s<rt_)) of 128 columns each
    const int stile = slice * qt + (slice < rt_ ? slice : rt_);
    const int jbase = stile * 128;
    const int jlen = (qt + (slice < rt_ ? 1 : 0)) * 128;

    const int prow = t >> 2, pjq = t & 3;            // P-compute role: 64 rows x 4 j-quads
    const int lane = t & 63, wv = t >> 6;
    const int l31 = lane & 31, lq = lane >> 5;
    const int wn0 = wv * 64;                         // wave's feature base

    const float fs = f_src[i0 + prow];
    const unsigned* maskRow = mask + (size_t)(i0 + prow) * NWRD + (jbase >> 5);
    const short* hb0 = h_t + (size_t)(wn0 + l31) * NN + jbase + lq * 8;
    const short* hb1 = hb0 + (size_t)32 * NN;

    float16v acc00 = {}, acc01 = {}, acc10 = {}, acc11 = {};
    float lp = 0.f;

    const int pswz = (prow & 7) << 4;
    const int rswz = (l31 & 7) << 4;
    const int wb = prow * 128 + pjq * 32;            // byte offset of this thread's P chunk
    const int ra = l31 * 128 + lq * 16;
    const int mshift = (pjq & 1) << 4;               // this thread's 16 bits within the word
    const int mword = pjq >> 1;

    unsigned mwCur, mwNext;

#define PPAIR(B0, B1, FI, PKI)                                          \
    {                                                                   \
        float y0 = fs + fdp[FI], y1 = fs + fdp[(FI) + 1];               \
        y0 = fmaxf(y0, 0.2f * y0); y1 = fmaxf(y1, 0.2f * y1);           \
        float p0 = (B0) ? EXP2(y0) : 0.f;                               \
        float p1 = (B1) ? EXP2(y1) : 0.f;                               \
        lp += p0 + p1;                                                  \
        pk[PKI] = cvt_pk_bf16(p0, p1);                                  \
    }

    for (int w0 = 0; w0 < jlen; w0 += FDWIN) {
        const int wl = (jlen - w0 < FDWIN) ? (jlen - w0) : FDWIN;
        // stage f_dst window once (8 floats/thread)
        if (t * 8 < wl) {
            *(float4v*)&Fdall[t * 8]     = *(const float4v*)(f_dst + jbase + w0 + t * 8);
            *(float4v*)&Fdall[t * 8 + 4] = *(const float4v*)(f_dst + jbase + w0 + t * 8 + 4);
        }
        __syncthreads();
        mwCur = maskRow[(w0 >> 5) + mword];          // first tile's mask word

        for (int jo = w0; jo < w0 + wl; jo += JTILE) {
            const int buf = (jo >> 6) & 1;
            // 1. B preload for THIS tile -- issued first; L2/L3 latency hides under P compute
            short8 b0_[4], b1_[4];
#pragma unroll
            for (int kk = 0; kk < 4; kk++) {
                b0_[kk] = *(const short8*)(hb0 + jo + kk * 16);
                b1_[kk] = *(const short8*)(hb1 + jo + kk * 16);
            }
            // 2. mask prefetch for NEXT tile (younger than B: B's vmcnt wait leaves it in flight)
            {
                const int jn = (jo + JTILE < w0 + wl) ? (jo + JTILE) : w0;
                mwNext = maskRow[(jn >> 5) + mword];
            }
            // 3. P compute from mwCur bits, pairwise cvt_pk pack
            {
                const float* fdp = &Fdall[jo - w0 + pjq * 16];
                const unsigned sm = mwCur >> mshift;
                unsigned pk[8];
                PPAIR((sm >> 0) & 1u,  (sm >> 1) & 1u,  0, 0)
                PPAIR((sm >> 2) & 1u,  (sm >> 3) & 1u,  2, 1)
                PPAIR((sm >> 4) & 1u,  (sm >> 5) & 1u,  4, 2)
                PPAIR((sm >> 6) & 1u,  (sm >> 7) & 1u,  6, 3)
                PPAIR((sm >> 8) & 1u,  (sm >> 9) & 1u,  8, 4)
                PPAIR((sm >> 10) & 1u, (sm >> 11) & 1u, 10, 5)
                PPAIR((sm >> 12) & 1u, (sm >> 13) & 1u, 12, 6)
                PPAIR((sm >> 14) & 1u, (sm >> 15) & 1u, 14, 7)
                char* pbuf_ = (char*)&Pt[buf][0];
                int4v lov, hiv;
                lov[0] = (int)pk[0]; lov[1] = (int)pk[1]; lov[2] = (int)pk[2]; lov[3] = (int)pk[3];
                hiv[0] = (int)pk[4]; hiv[1] = (int)pk[5]; hiv[2] = (int)pk[6]; hiv[3] = (int)pk[7];
                *(int4v*)(pbuf_ + (wb ^ pswz)) = lov;
                *(int4v*)(pbuf_ + ((wb + 16) ^ pswz)) = hiv;
            }
            // 4. barrier: drain LDS only, keep global loads in flight
            asm volatile("s_waitcnt lgkmcnt(0)\n\ts_barrier" ::: "memory");
            // 5. MFMA phase
            __builtin_amdgcn_s_setprio(1);
            {
                const char* pbuf_ = (const char*)&Pt[buf][0];
#pragma unroll
                for (int kk = 0; kk < 4; kk++) {
                    short8 a0_ = *(const short8*)(pbuf_ + ((ra + kk * 32) ^ rswz));
                    short8 a1_ = *(const short8*)(pbuf_ + ((ra + 4096 + kk * 32) ^ rswz));
                    acc00 = __builtin_amdgcn_mfma_f32_32x32x16_bf16(a0_, b0_[kk], acc00, 0, 0, 0);
                    acc01 = __builtin_amdgcn_mfma_f32_32x32x16_bf16(a0_, b1_[kk], acc01, 0, 0, 0);
                    acc10 = __builtin_amdgcn_mfma_f32_32x32x16_bf16(a1_, b0_[kk], acc10, 0, 0, 0);
                    acc11 = __builtin_amdgcn_mfma_f32_32x32x16_bf16(a1_, b1_[kk], acc11, 0, 0, 0);
                }
            }
            __builtin_amdgcn_s_setprio(0);
            mwCur = mwNext;                          // 1-reg copy; L3 latency long since covered
        }
    }
#undef PPAIR

    // ---- epilogue: partial row-sum l, partial O ----
    lp += __shfl_xor(lp, 1);
    lp += __shfl_xor(lp, 2);
    if (pjq == 0) lpart[slice * NN + i0 + prow] = lp;

    float* obase = Opart + ((size_t)slice * NN + i0) * FOUT;
    // C/D 32x32: col = l31, row = (reg&3) + 8*(reg>>2) + 4*lq
#pragma unroll
    for (int rt = 0; rt < 2; rt++) {
#pragma unroll
        for (int nt = 0; nt < 2; nt++) {
            const float16v& av = rt == 0 ? (nt == 0 ? acc00 : acc01) : (nt == 0 ? acc10 : acc11);
#pragma unroll
            for (int reg = 0; reg < 16; reg++) {
                int row = rt * 32 + (reg & 3) + 8 * (reg >> 2) + 4 * lq;
                int n = wn0 + nt * 32 + l31;
                obase[(size_t)row * FOUT + n] = av[reg];
            }
        }
    }
}

// ---------------- Kernel 3: combine partials: out = sum_s O_s / sum_s l_s ----------------
__global__ __launch_bounds__(256) void combine_kernel(const float* __restrict__ Opart,
                                                      const float* __restrict__ lpart,
                                                      float* __restrict__ out, int slices) {
    int i = blockIdx.x, n = threadIdx.x;
    float o = 0.f, l = 0.f;
    for (int s = 0; s < slices; s++) {
        o += Opart[((size_t)s * NN + i) * FOUT + n];
        l += lpart[s * NN + i];
    }
    out[(size_t)i * FOUT + n] = o / l;
}

extern "C" void kernel_launch(void* const* d_in, const int* in_sizes, int n_in,
                              void* d_out, int out_size, void* d_ws, size_t ws_size,
                              hipStream_t stream) {
    const float* x   = (const float*)d_in[0];
    const int*   adj = (const int*)d_in[1];
    const float* W   = (const float*)d_in[2];
    const float* a   = (const float*)d_in[3];
    float* out = (float*)d_out;

    char* ws = (char*)d_ws;
    short* h_t   = (short*)ws;                                   // 4 MB
    short* Wt    = (short*)(ws + (4u << 20));                    // 256 KB
    float* f_src = (float*)(ws + (4u << 20) + (256u << 10));     // 32 KB
    float* f_dst = (float*)(ws + (4u << 20) + (288u << 10));     // 32 KB
    float* lpart = (float*)(ws + (4u << 20) + (320u << 10));     // up to 256 KB (8 slices)
    float* Opart = (float*)(ws + (5u << 20));                    // slices x 8 MB

    const size_t OSLICE = (size_t)NN * FOUT * 4;                 // 8 MB per slice
    const size_t MASKSZ = (size_t)NN * NN / 8;                   // 8 MB bitmask
    int slices = 1;
    if (ws_size >= (size_t)(5u << 20) + 6 * OSLICE + MASKSZ) slices = 6;  // grid 768 = 3/CU exact
    else if (ws_size >= (size_t)(5u << 20) + 4 * OSLICE + MASKSZ) slices = 4;
    else if (ws_size >= (size_t)(5u << 20) + 2 * OSLICE + MASKSZ) slices = 2;
    unsigned* mask = (unsigned*)(ws + (5u << 20) + (size_t)slices * OSLICE);
    const int NTILES = NN / 128;                                 // 64 tiles of 128 cols
    int qt = NTILES / slices, rt_ = NTILES % slices;

    hipMemsetAsync(f_src, 0, 2 * NN * sizeof(float), stream);
    wt_kernel<<<dim3(FIN / 32, FOUT / 32), 256, 0, stream>>>(W, Wt);
    hm_kernel<<<2560, 256, 0, stream>>>(x, Wt, a, adj, h_t, f_src, f_dst, mask);
    gat_kernel<<<dim3(NN / 64, slices), 256, 0, stream>>>(mask, h_t, f_src, f_dst,
                                                          Opart, lpart, qt, rt_);
    combine_kernel<<<NN, 256, 0, stream>>>(Opart, lpart, out, slices);
}

// Round 8
// 459.621 us; speedup vs baseline: 1.2140x; 1.2140x over previous
//
#include <hip/hip_runtime.h>
#include <hip/hip_bf16.h>

#define NN 8192
#define FIN 512
#define FOUT 256
#define JTILE 64
#define FDWIN 2048
#define NWRD (NN / 32)     // 256 mask words per row

typedef __attribute__((ext_vector_type(8))) short short8;
typedef __attribute__((ext_vector_type(4))) float float4v;
typedef __attribute__((ext_vector_type(4))) int int4v;
typedef __attribute__((ext_vector_type(16))) float float16v;

#if __has_builtin(__builtin_amdgcn_exp2f)
#define EXP2(x) __builtin_amdgcn_exp2f(x)
#else
#define EXP2(x) exp2f(x)
#endif

__device__ __forceinline__ short f2bf(float f) {
    union { float f; unsigned u; } v; v.f = f;
    unsigned r = (v.u + 0x7FFFu + ((v.u >> 16) & 1u)) >> 16;
    return (short)r;
}

// pack 2 f32 -> 2 bf16 (RNE), lo -> D[15:0], hi -> D[31:16]
__device__ __forceinline__ unsigned cvt_pk_bf16(float lo, float hi) {
    unsigned r;
    asm("v_cvt_pk_bf16_f32 %0, %1, %2" : "=v"(r) : "v"(lo), "v"(hi));
    return r;
}

// ---------------- Kernel 0: Wt[n][k] = bf16(W[k][n]), tiled transpose ----------------
__global__ __launch_bounds__(256) void wt_kernel(const float* __restrict__ W,
                                                 short* __restrict__ Wt) {
    __shared__ short tile[32][33];
    int tx = threadIdx.x & 31, ty = threadIdx.x >> 5;   // 32 x 8
    int k0 = blockIdx.x * 32, n0 = blockIdx.y * 32;
#pragma unroll
    for (int r = 0; r < 32; r += 8)
        tile[ty + r][tx] = f2bf(W[(size_t)(k0 + ty + r) * FOUT + n0 + tx]);
    __syncthreads();
#pragma unroll
    for (int r = 0; r < 32; r += 8)
        Wt[(size_t)(n0 + ty + r) * FIN + k0 + tx] = tile[tx][ty + r];
}

// ---------------- Kernel 1 (fused): blocks [0,512) = h/f_src/f_dst; [512,2560) = adj->bitmask ----
// Mask part v2 (r6 ran 2.0 TB/s: per-lane stride-128B dwordx4 touched 64 cache lines
// per instruction -- request-rate capped). Now: wave = one adj row; lane i reads the two
// int4s at bytes [32i,32i+32) -- DENSE per instruction pair; emits one mask BYTE for its
// 8 ints (little-endian byte order == gat's uint32 word reads). 64B contiguous wave store.
__global__ __launch_bounds__(256) void hm_kernel(const float* __restrict__ x,
                                                 const short* __restrict__ Wt,
                                                 const float* __restrict__ a,
                                                 const int* __restrict__ adj,
                                                 short* __restrict__ h_t,
                                                 float* __restrict__ f_src,
                                                 float* __restrict__ f_dst,
                                                 unsigned* __restrict__ mask) {
    if (blockIdx.x >= 512) {
        const int mb = blockIdx.x - 512;                 // 0..2047
        const int wid = threadIdx.x >> 6, lane = threadIdx.x & 63;
        const int row = mb * 4 + wid;                    // one adj row per wave
        const int* rowp = adj + (size_t)row * NN + lane * 8;
        unsigned char* mrow = (unsigned char*)mask + (size_t)row * (NN / 8) + lane;
#pragma unroll 4
        for (int it = 0; it < 16; it++) {
            const int4v* p = (const int4v*)(rowp + it * 512);
            int4v v0 = __builtin_nontemporal_load(p);
            int4v v1 = __builtin_nontemporal_load(p + 1);
            unsigned b = 0;
            b |= (v0[0] != 0 ? 1u : 0u);
            b |= (v0[1] != 0 ? 2u : 0u);
            b |= (v0[2] != 0 ? 4u : 0u);
            b |= (v0[3] != 0 ? 8u : 0u);
            b |= (v1[0] != 0 ? 16u : 0u);
            b |= (v1[1] != 0 ? 32u : 0u);
            b |= (v1[2] != 0 ? 64u : 0u);
            b |= (v1[3] != 0 ? 128u : 0u);
            mrow[it * 64] = (unsigned char)b;
        }
        return;
    }
    // ---- h part ----
    int wave = (blockIdx.x << 2) + (threadIdx.x >> 6);
    int lane = threadIdx.x & 63;
    int m0 = (wave & 511) << 4;
    int n0 = (wave >> 9) << 6;
    int lr = lane & 15, lq = lane >> 4;

    const float* xrow = x + (size_t)(m0 + lr) * FIN + lq * 8;
    const short* wbase = Wt + (size_t)(n0 + lr) * FIN + lq * 8;

    float4v acc[4] = {};
    for (int k0 = 0; k0 < FIN; k0 += 32) {
        float4v xa = *(const float4v*)(xrow + k0);
        float4v xb = *(const float4v*)(xrow + k0 + 4);
        short8 av;
        av[0] = f2bf(xa[0]); av[1] = f2bf(xa[1]); av[2] = f2bf(xa[2]); av[3] = f2bf(xa[3]);
        av[4] = f2bf(xb[0]); av[5] = f2bf(xb[1]); av[6] = f2bf(xb[2]); av[7] = f2bf(xb[3]);
#pragma unroll
        for (int ct = 0; ct < 4; ct++) {
            short8 bv = *(const short8*)(wbase + (size_t)ct * 16 * FIN + k0);
            acc[ct] = __builtin_amdgcn_mfma_f32_16x16x32_bf16(av, bv, acc[ct], 0, 0, 0);
        }
    }
    float s_part[4] = {0.f, 0.f, 0.f, 0.f};
    float d_part[4] = {0.f, 0.f, 0.f, 0.f};
#pragma unroll
    for (int ct = 0; ct < 4; ct++) {
        int n = n0 + ct * 16 + lr;
        float al = a[n], ar = a[FOUT + n];
#pragma unroll
        for (int reg = 0; reg < 4; reg++) {
            float hv = acc[ct][reg];
            s_part[reg] = fmaf(hv, al, s_part[reg]);
            d_part[reg] = fmaf(hv, ar, d_part[reg]);
            h_t[(size_t)n * NN + (m0 + lq * 4 + reg)] = f2bf(hv);
        }
    }
#pragma unroll
    for (int off = 1; off < 16; off <<= 1) {
#pragma unroll
        for (int reg = 0; reg < 4; reg++) {
            s_part[reg] += __shfl_xor(s_part[reg], off);
            d_part[reg] += __shfl_xor(d_part[reg], off);
        }
    }
    const float LOG2E = 1.4426950408889634f;
    if (lr == 0) {
#pragma unroll
        for (int reg = 0; reg < 4; reg++) {
            atomicAdd(&f_src[m0 + lq * 4 + reg], s_part[reg] * LOG2E);
            atomicAdd(&f_dst[m0 + lq * 4 + reg], d_part[reg] * LOG2E);
        }
    }
}

// ---------------- Kernel 2: fused masked-softmax-numerator @ h (j-sliced) ----------------
// v6: adj replaced by 8MB L3-resident bitmask (1 uint32 load per thread per tile,
// prefetched 1 tile ahead). Peak live ~130 << 170 @ (256,3). Unchanged from r6 (gat ~50us).
__global__ __launch_bounds__(256, 3) void gat_kernel(const unsigned* __restrict__ mask,
                                                     const short* __restrict__ h_t,
                                                     const float* __restrict__ f_src,
                                                     const float* __restrict__ f_dst,
                                                     float* __restrict__ Opart,
                                                     float* __restrict__ lpart,
                                                     int qt, int rt_) {
    __shared__ short Pt[2][64 * 64];   // [row][j], XOR-swizzled (byte ^= (row&7)<<4), 2x8KB
    __shared__ float Fdall[FDWIN];     // f_dst window (<=8KB), staged once per window

    const int t = threadIdx.x;
    const int i0 = blockIdx.x * 64;
    const int slice = blockIdx.y;
    const int stile = slice * qt + (slice < rt_ ? slice : rt_);
    const int jbase = stile * 128;
    const int jlen = (qt + (slice < rt_ ? 1 : 0)) * 128;

    const int prow = t >> 2, pjq = t & 3;            // P-compute role: 64 rows x 4 j-quads
    const int lane = t & 63, wv = t >> 6;
    const int l31 = lane & 31, lq = lane >> 5;
    const int wn0 = wv * 64;                         // wave's feature base

    const float fs = f_src[i0 + prow];
    const unsigned* maskRow = mask + (size_t)(i0 + prow) * NWRD + (jbase >> 5);
    const short* hb0 = h_t + (size_t)(wn0 + l31) * NN + jbase + lq * 8;
    const short* hb1 = hb0 + (size_t)32 * NN;

    float16v acc00 = {}, acc01 = {}, acc10 = {}, acc11 = {};
    float lp = 0.f;

    const int pswz = (prow & 7) << 4;
    const int rswz = (l31 & 7) << 4;
    const int wb = prow * 128 + pjq * 32;            // byte offset of this thread's P chunk
    const int ra = l31 * 128 + lq * 16;
    const int mshift = (pjq & 1) << 4;               // this thread's 16 bits within the word
    const int mword = pjq >> 1;

    unsigned mwCur, mwNext;

#define PPAIR(B0, B1, FI, PKI)                                          \
    {                                                                   \
        float y0 = fs + fdp[FI], y1 = fs + fdp[(FI) + 1];               \
        y0 = fmaxf(y0, 0.2f * y0); y1 = fmaxf(y1, 0.2f * y1);           \
        float p0 = (B0) ? EXP2(y0) : 0.f;                               \
        float p1 = (B1) ? EXP2(y1) : 0.f;                               \
        lp += p0 + p1;                                                  \
        pk[PKI] = cvt_pk_bf16(p0, p1);                                  \
    }

    for (int w0 = 0; w0 < jlen; w0 += FDWIN) {
        const int wl = (jlen - w0 < FDWIN) ? (jlen - w0) : FDWIN;
        if (t * 8 < wl) {
            *(float4v*)&Fdall[t * 8]     = *(const float4v*)(f_dst + jbase + w0 + t * 8);
            *(float4v*)&Fdall[t * 8 + 4] = *(const float4v*)(f_dst + jbase + w0 + t * 8 + 4);
        }
        __syncthreads();
        mwCur = maskRow[(w0 >> 5) + mword];          // first tile's mask word

        for (int jo = w0; jo < w0 + wl; jo += JTILE) {
            const int buf = (jo >> 6) & 1;
            // 1. B preload for THIS tile -- issued first; L2/L3 latency hides under P compute
            short8 b0_[4], b1_[4];
#pragma unroll
            for (int kk = 0; kk < 4; kk++) {
                b0_[kk] = *(const short8*)(hb0 + jo + kk * 16);
                b1_[kk] = *(const short8*)(hb1 + jo + kk * 16);
            }
            // 2. mask prefetch for NEXT tile (younger than B: B's vmcnt wait leaves it in flight)
            {
                const int jn = (jo + JTILE < w0 + wl) ? (jo + JTILE) : w0;
                mwNext = maskRow[(jn >> 5) + mword];
            }
            // 3. P compute from mwCur bits, pairwise cvt_pk pack
            {
                const float* fdp = &Fdall[jo - w0 + pjq * 16];
                const unsigned sm = mwCur >> mshift;
                unsigned pk[8];
                PPAIR((sm >> 0) & 1u,  (sm >> 1) & 1u,  0, 0)
                PPAIR((sm >> 2) & 1u,  (sm >> 3) & 1u,  2, 1)
                PPAIR((sm >> 4) & 1u,  (sm >> 5) & 1u,  4, 2)
                PPAIR((sm >> 6) & 1u,  (sm >> 7) & 1u,  6, 3)
                PPAIR((sm >> 8) & 1u,  (sm >> 9) & 1u,  8, 4)
                PPAIR((sm >> 10) & 1u, (sm >> 11) & 1u, 10, 5)
                PPAIR((sm >> 12) & 1u, (sm >> 13) & 1u, 12, 6)
                PPAIR((sm >> 14) & 1u, (sm >> 15) & 1u, 14, 7)
                char* pbuf_ = (char*)&Pt[buf][0];
                int4v lov, hiv;
                lov[0] = (int)pk[0]; lov[1] = (int)pk[1]; lov[2] = (int)pk[2]; lov[3] = (int)pk[3];
                hiv[0] = (int)pk[4]; hiv[1] = (int)pk[5]; hiv[2] = (int)pk[6]; hiv[3] = (int)pk[7];
                *(int4v*)(pbuf_ + (wb ^ pswz)) = lov;
                *(int4v*)(pbuf_ + ((wb + 16) ^ pswz)) = hiv;
            }
            // 4. barrier: drain LDS only, keep global loads in flight
            asm volatile("s_waitcnt lgkmcnt(0)\n\ts_barrier" ::: "memory");
            // 5. MFMA phase
            __builtin_amdgcn_s_setprio(1);
            {
                const char* pbuf_ = (const char*)&Pt[buf][0];
#pragma unroll
                for (int kk = 0; kk < 4; kk++) {
                    short8 a0_ = *(const short8*)(pbuf_ + ((ra + kk * 32) ^ rswz));
                    short8 a1_ = *(const short8*)(pbuf_ + ((ra + 4096 + kk * 32) ^ rswz));
                    acc00 = __builtin_amdgcn_mfma_f32_32x32x16_bf16(a0_, b0_[kk], acc00, 0, 0, 0);
                    acc01 = __builtin_amdgcn_mfma_f32_32x32x16_bf16(a0_, b1_[kk], acc01, 0, 0, 0);
                    acc10 = __builtin_amdgcn_mfma_f32_32x32x16_bf16(a1_, b0_[kk], acc10, 0, 0, 0);
                    acc11 = __builtin_amdgcn_mfma_f32_32x32x16_bf16(a1_, b1_[kk], acc11, 0, 0, 0);
                }
            }
            __builtin_amdgcn_s_setprio(0);
            mwCur = mwNext;
        }
    }
#undef PPAIR

    // ---- epilogue: partial row-sum l, partial O ----
    lp += __shfl_xor(lp, 1);
    lp += __shfl_xor(lp, 2);
    if (pjq == 0) lpart[slice * NN + i0 + prow] = lp;

    float* obase = Opart + ((size_t)slice * NN + i0) * FOUT;
    // C/D 32x32: col = l31, row = (reg&3) + 8*(reg>>2) + 4*lq
#pragma unroll
    for (int rt = 0; rt < 2; rt++) {
#pragma unroll
        for (int nt = 0; nt < 2; nt++) {
            const float16v& av = rt == 0 ? (nt == 0 ? acc00 : acc01) : (nt == 0 ? acc10 : acc11);
#pragma unroll
            for (int reg = 0; reg < 16; reg++) {
                int row = rt * 32 + (reg & 3) + 8 * (reg >> 2) + 4 * lq;
                int n = wn0 + nt * 32 + l31;
                obase[(size_t)row * FOUT + n] = av[reg];
            }
        }
    }
}

// ---------------- Kernel 3: combine partials: out = sum_s O_s / sum_s l_s ----------------
__global__ __launch_bounds__(256) void combine_kernel(const float* __restrict__ Opart,
                                                      const float* __restrict__ lpart,
                                                      float* __restrict__ out, int slices) {
    int i = blockIdx.x, n = threadIdx.x;
    float o = 0.f, l = 0.f;
    for (int s = 0; s < slices; s++) {
        o += Opart[((size_t)s * NN + i) * FOUT + n];
        l += lpart[s * NN + i];
    }
    out[(size_t)i * FOUT + n] = o / l;
}

extern "C" void kernel_launch(void* const* d_in, const int* in_sizes, int n_in,
                              void* d_out, int out_size, void* d_ws, size_t ws_size,
                              hipStream_t stream) {
    const float* x   = (const float*)d_in[0];
    const int*   adj = (const int*)d_in[1];
    const float* W   = (const float*)d_in[2];
    const float* a   = (const float*)d_in[3];
    float* out = (float*)d_out;

    char* ws = (char*)d_ws;
    short* h_t   = (short*)ws;                                   // 4 MB
    short* Wt    = (short*)(ws + (4u << 20));                    // 256 KB
    float* f_src = (float*)(ws + (4u << 20) + (256u << 10));     // 32 KB
    float* f_dst = (float*)(ws + (4u << 20) + (288u << 10));     // 32 KB
    float* lpart = (float*)(ws + (4u << 20) + (320u << 10));     // up to 256 KB
    float* Opart = (float*)(ws + (5u << 20));                    // slices x 8 MB

    const size_t OSLICE = (size_t)NN * FOUT * 4;                 // 8 MB per slice
    const size_t MASKSZ = (size_t)NN * NN / 8;                   // 8 MB bitmask
    int slices = 1;
    if (ws_size >= (size_t)(5u << 20) + 6 * OSLICE + MASKSZ) slices = 6;  // grid 768 = 3/CU exact
    else if (ws_size >= (size_t)(5u << 20) + 4 * OSLICE + MASKSZ) slices = 4;
    else if (ws_size >= (size_t)(5u << 20) + 2 * OSLICE + MASKSZ) slices = 2;
    unsigned* mask = (unsigned*)(ws + (5u << 20) + (size_t)slices * OSLICE);
    const int NTILES = NN / 128;                                 // 64 tiles of 128 cols
    int qt = NTILES / slices, rt_ = NTILES % slices;

    hipMemsetAsync(f_src, 0, 2 * NN * sizeof(float), stream);
    wt_kernel<<<dim3(FIN / 32, FOUT / 32), 256, 0, stream>>>(W, Wt);
    hm_kernel<<<2560, 256, 0, stream>>>(x, Wt, a, adj, h_t, f_src, f_dst, mask);
    gat_kernel<<<dim3(NN / 64, slices), 256, 0, stream>>>(mask, h_t, f_src, f_dst,
                                                          Opart, lpart, qt, rt_);
    combine_kernel<<<NN, 256, 0, stream>>>(Opart, lpart, out, slices);
}